// Round 4
// baseline (572.044 us; speedup 1.0000x reference)
//
#include <hip/hip_runtime.h>
#include <hip/hip_bf16.h>
#include <math.h>

// Problem constants (fixed by reference)
#define B_ 2
#define S_ 2048
#define D_ 1024
#define M_ (B_*S_)      // 4096 rows
#define CTXLD 3072      // fused ctx row stride: [short | medium | long]

typedef _Float16 half8_t __attribute__((ext_vector_type(8)));
typedef _Float16 half4_t __attribute__((ext_vector_type(4)));
typedef float    f32x4  __attribute__((ext_vector_type(4)));

// async global->LDS: per-lane global addr; HW scatters lane i to (uniform LDS base) + i*16B
#define GL2LDS(g, l) __builtin_amdgcn_global_load_lds( \
    (const __attribute__((address_space(1))) void*)(uintptr_t)(g), \
    (__attribute__((address_space(3))) void*)(l), 16, 0, 0)

// ---------------------------------------------------------------------------
// Batched fp16-MFMA GEMM: C = A @ W^T + bias. BK=64 chunk-major.
// 128x128 tile, 4 waves. batch dim selects {b0,b1,b2}.
// MODE 0: C fp32 + bias. MODE 1: C fp16 + bias.
// MODE 2: QKV split (cols<2048 -> qk fp16 ldc; cols>=2048 -> vT transposed).
// MODE 3: C fp16, no bias (Weff prep).
// SWZ remap available but currently unused: r3 measured it cost ~8us on the
// QKV dispatch (A-refetch 3x outweighed W-panel L2 hits). Kept for reference.
// ---------------------------------------------------------------------------
struct GemmBatch {
    const _Float16* A;
    const _Float16* W;
    const float*    bias;
    void*           C;
    void*           C2;
};

template<int MODE, bool SWZ>
__global__ __launch_bounds__(256) void gemm_f16(
    GemmBatch b0, GemmBatch b1, GemmBatch b2, int lda, int ldw, int ldc, int K)
{
    __shared__ __align__(16) _Float16 As[2*128*32];
    __shared__ __align__(16) _Float16 Bs[2*128*32];

    int bx, by, bz;
    if (SWZ) {
        const int gx = gridDim.x, gy = gridDim.y;
        const int total = gx * gy * gridDim.z;
        const int lin = blockIdx.x + gx * (blockIdx.y + gy * blockIdx.z);
        const int lbid = (lin & 7) * (total >> 3) + (lin >> 3);
        bx = lbid % gx;
        const int rem = lbid / gx;
        by = rem % gy;
        bz = rem / gy;
    } else {
        bx = blockIdx.x; by = blockIdx.y; bz = blockIdx.z;
    }

    const GemmBatch G = (bz == 0) ? b0 : ((bz == 1) ? b1 : b2);

    const int t = threadIdx.x, lane = t & 63, w = t >> 6;
    const int bm = bx * 128, bn = by * 128;
    const int wm = (w >> 1) * 64, wn = (w & 1) * 64;
    const int fr = lane & 15, q8 = (lane >> 4) * 8;
    const int srow = lane >> 2, scol = (lane & 3) * 8;

    f32x4 acc[4][4] = {};

    const _Float16* Ab = G.A + (size_t)(bm + w*32 + srow) * lda + scol;
    const _Float16* Wb = G.W + (size_t)(bn + w*32 + srow) * ldw + scol;

    for (int k0 = 0; k0 < K; k0 += 64) {
        __syncthreads();
        #pragma unroll
        for (int kc = 0; kc < 2; kc++)
            #pragma unroll
            for (int ii = 0; ii < 2; ii++) {
                GL2LDS(Ab + (size_t)(ii*16)*lda + k0 + kc*32,
                       As + kc*4096 + w*1024 + ii*512);
                GL2LDS(Wb + (size_t)(ii*16)*ldw + k0 + kc*32,
                       Bs + kc*4096 + w*1024 + ii*512);
            }
        __syncthreads();
        #pragma unroll
        for (int kc = 0; kc < 2; kc++) {
            half8_t af[4], bf[4];
            #pragma unroll
            for (int mt = 0; mt < 4; mt++)
                af[mt] = *(const half8_t*)&As[kc*4096 + (wm + mt*16 + fr)*32 + q8];
            #pragma unroll
            for (int nt = 0; nt < 4; nt++)
                bf[nt] = *(const half8_t*)&Bs[kc*4096 + (wn + nt*16 + fr)*32 + q8];
            #pragma unroll
            for (int mt = 0; mt < 4; mt++)
                #pragma unroll
                for (int nt = 0; nt < 4; nt++)
                    acc[mt][nt] = __builtin_amdgcn_mfma_f32_16x16x32_f16(
                        af[mt], bf[nt], acc[mt][nt], 0, 0, 0);
        }
    }

    const int cl = lane & 15;
    const int rq = (lane >> 4) * 4;

    if (MODE == 2 && bn >= 2048) {
        #pragma unroll
        for (int mt = 0; mt < 4; mt++) {
            int row0 = bm + wm + mt*16 + rq;
            #pragma unroll
            for (int nt = 0; nt < 4; nt++) {
                int gcol = bn + wn + nt*16 + cl;
                float bv = G.bias[gcol];
                half4_t hv = {(_Float16)(acc[mt][nt][0] + bv),
                              (_Float16)(acc[mt][nt][1] + bv),
                              (_Float16)(acc[mt][nt][2] + bv),
                              (_Float16)(acc[mt][nt][3] + bv)};
                *(half4_t*)((_Float16*)G.C2 + (size_t)(gcol - 2048) * M_ + row0) = hv;
            }
        }
        return;
    }

    #pragma unroll
    for (int mt = 0; mt < 4; mt++) {
        #pragma unroll
        for (int r = 0; r < 4; r++) {
            size_t grow = (size_t)(bm + wm + mt*16 + rq + r);
            #pragma unroll
            for (int nt = 0; nt < 4; nt++) {
                int gcol = bn + wn + nt*16 + cl;
                float v = acc[mt][nt][r] + ((MODE == 3) ? 0.f : G.bias[gcol]);
                if (MODE == 0)
                    ((float*)G.C)[grow * ldc + gcol] = v;
                else
                    ((_Float16*)G.C)[grow * ldc + gcol] = (_Float16)v;
            }
        }
    }
}

// ---------------------------------------------------------------------------
// Fused fp32 -> fp16 cast (5 tensors: x, w_in x3, w_comb).
// ---------------------------------------------------------------------------
struct CastArgs {
    const float* s[5];
    _Float16*    d[5];
    int          nb[5];
};

__global__ __launch_bounds__(256) void cast_all(CastArgs a)
{
    int off = blockIdx.x;
    int seg = 0;
    while (seg < 4 && off >= a.nb[seg]) { off -= a.nb[seg]; seg++; }
    int i = off * 256 + threadIdx.x;
    float4 v = ((const float4*)a.s[seg])[i];
    half4_t h = {(_Float16)v.x, (_Float16)v.y, (_Float16)v.z, (_Float16)v.w};
    ((half4_t*)a.d[seg])[i] = h;
}

// ---------------------------------------------------------------------------
// Transposing cast for wo_* : in fp32 [1024 d][1024 e] -> out fp16 [e][d].
// ---------------------------------------------------------------------------
__global__ __launch_bounds__(256) void transpose_cast_wo(
    const float* s0, const float* s1, const float* s2,
    _Float16* d0, _Float16* d1, _Float16* d2)
{
    __shared__ float T[64][68];
    const float* src = blockIdx.z == 0 ? s0 : (blockIdx.z == 1 ? s1 : s2);
    _Float16*    dst = blockIdx.z == 0 ? d0 : (blockIdx.z == 1 ? d1 : d2);
    const int db = blockIdx.x * 64;
    const int eb = blockIdx.y * 64;
    const int r = threadIdx.x >> 4;
    const int c = (threadIdx.x & 15) * 4;

    #pragma unroll
    for (int rr = 0; rr < 4; rr++) {
        float4 v = *(const float4*)&src[(size_t)(db + rr*16 + r)*1024 + eb + c];
        T[rr*16 + r][c+0] = v.x; T[rr*16 + r][c+1] = v.y;
        T[rr*16 + r][c+2] = v.z; T[rr*16 + r][c+3] = v.w;
    }
    __syncthreads();
    #pragma unroll
    for (int rr = 0; rr < 4; rr++) {
        int e = rr*16 + r;
        half4_t hv = {(_Float16)T[c+0][e], (_Float16)T[c+1][e],
                      (_Float16)T[c+2][e], (_Float16)T[c+3][e]};
        *(half4_t*)&dst[(size_t)(eb + e)*1024 + db + c] = hv;
    }
}

// ---------------------------------------------------------------------------
// beff[n] = b_comb[n] + sum_d bo_s[d] Wc[n][d] + bo_m[d] Wc[n][1024+d] + bo_l[d] Wc[n][2048+d]
// ---------------------------------------------------------------------------
__global__ __launch_bounds__(256) void beff_kernel(
    const float* __restrict__ w_comb, const float* __restrict__ b_comb,
    const float* __restrict__ bo_s, const float* __restrict__ bo_m,
    const float* __restrict__ bo_l, float* __restrict__ beff)
{
    __shared__ float red[4];
    const int n = blockIdx.x, t = threadIdx.x;
    float s = 0.f;
    for (int d = t; d < 1024; d += 256)
        s += w_comb[(size_t)n*3072 + d]        * bo_s[d]
           + w_comb[(size_t)n*3072 + 1024 + d] * bo_m[d]
           + w_comb[(size_t)n*3072 + 2048 + d] * bo_l[d];
    #pragma unroll
    for (int m = 32; m >= 1; m >>= 1) s += __shfl_xor(s, m);
    if ((t & 63) == 0) red[t >> 6] = s;
    __syncthreads();
    if (t == 0) beff[n] = b_comb[n] + red[0] + red[1] + red[2] + red[3];
}

// ---------------------------------------------------------------------------
// Flash attention body — 2-phase double-buffered pipeline (r4).
// LDS (halfs): KV[2][2*DK*BJ] | Ps [4*16*40]. DK*BJ = 8192 both
// instantiations -> 2*16384 + 2560 = 35328 halfs = 70.7KB -> 2 blocks/CU.
//
// Round r: barrier -> STAGE(r+1 -> buf^1) -> compute(buf) -> flip.
// One barrier/round (was 2); the vmcnt(0) drain at the barrier lands after
// a full compute phase has covered the stage latency (T3-minimum recipe).
// Race audit: barrier at r (a) drains stage of buf[r&1] issued at r-1,
// (b) orders r-1's LDS reads of buf[(r-1)&1] before its re-stage. Ps is
// per-wave (same-wave DS ordering), unaffected by the barrier change.
//
// T2 bank-conflict swizzle (r2): XOR 16B slot with (row>>1)&3 via
// pre-swizzled global source + swizzled read (BANK_CONFLICT 2.2e7->4.9e6).
// T1 XCD remap in flash_mega (r3): FETCH 364MB->44MB.
// ---------------------------------------------------------------------------
template<int DK, int BJ, bool LOUT>
__device__ __forceinline__ void flash_body(
    _Float16* lds, float* Lw,
    const _Float16* __restrict__ qk, const _Float16* __restrict__ vT,
    _Float16* __restrict__ ctx, float* __restrict__ lout,
    int window, int b, int h, int qblk, int H)
{
    constexpr int KS   = DK / 32;     // k-chunks
    constexpr int DT   = DK / 16;     // PV d-tiles
    constexpr int JT   = BJ / 16;     // j-subtiles per round
    constexpr int JC   = BJ / 32;     // j-chunks per round (PV kc count)
    constexpr int LDP  = 40;
    constexpr int KVSZ = 2 * DK * BJ; // one K+V buffer (halfs)

    _Float16* Ps = lds + 2 * KVSZ;

    const int t = threadIdx.x, lane = t & 63, w = t >> 6;
    const int fr = lane & 15, g = lane >> 4, k8 = g * 8;
    // swizzled LDS fragment slot: slot g holds global chunk g^((row>>1)&3)
    const int k8s = (g ^ ((fr >> 1) & 3)) * 8;
    const int blkQ = qblk * 64;
    const int qlo  = blkQ + w * 16;

    const float sc = ((DK == 128) ? 0.08838834764831845f : 0.125f) * 1.44269504f;

    _Float16* PsW = Ps + w * 16 * LDP;
    const int srow = lane >> 2;
    // stage-side inverse swizzle of the global source chunk
    const int ssw  = ((lane & 3) ^ ((srow >> 1) & 3)) * 8;

    half8_t qf[KS];
    #pragma unroll
    for (int kk = 0; kk < KS; kk++)
        qf[kk] = *(const half8_t*)&qk[(size_t)(b*S_ + qlo + fr)*2048 + h*DK + kk*32 + k8];

    f32x4 O[DT] = {};
    float lsum = 0.f;

    // first kept round: smallest multiple of BJ with j0 + BJ - 1 >= blkQ - window
    int jstart = 0;
    if (window >= 0) {
        int lo = blkQ - window - BJ + 1;
        if (lo > 0) jstart = ((lo + BJ - 1) / BJ) * BJ;
    }

    auto stage = [&](int j0, int buf) {
        _Float16* Kb = lds + buf * KVSZ;
        _Float16* Vb = Kb + DK * BJ;
        // K: [kchunk][BJ rows][32]; wave w rows w*(BJ/4)+ii*16+srow
        #pragma unroll
        for (int kk = 0; kk < KS; kk++)
            #pragma unroll
            for (int ii = 0; ii < BJ/64; ii++)
                GL2LDS(&qk[(size_t)(b*S_ + j0 + w*(BJ/4) + ii*16 + srow)*2048
                           + 1024 + h*DK + kk*32 + ssw],
                       &Kb[kk*BJ*32 + w*(BJ/4)*32 + ii*512]);
        // vT: [jchunk][DK rows][32]; wave w d-rows w*(DK/4)+ii*16+srow
        #pragma unroll
        for (int jc = 0; jc < JC; jc++)
            #pragma unroll
            for (int ii = 0; ii < DK/64; ii++)
                GL2LDS(&vT[(size_t)(h*DK + w*(DK/4) + ii*16 + srow)*M_
                           + b*S_ + j0 + jc*32 + ssw],
                       &Vb[jc*DK*32 + w*(DK/4)*32 + ii*512]);
    };

    stage(jstart, 0);
    int cur = 0;

    for (int j0 = jstart; j0 < S_; j0 += BJ) {
        __syncthreads();
        if (j0 + BJ < S_) stage(j0 + BJ, cur ^ 1);

        _Float16* Ks = lds + cur * KVSZ;
        _Float16* Vs = Ks + DK * BJ;

        f32x4 st[JT];
        #pragma unroll
        for (int jt = 0; jt < JT; jt++) {
            f32x4 s = {};
            #pragma unroll
            for (int kk = 0; kk < KS; kk++) {
                half8_t kf = *(const half8_t*)&Ks[kk*BJ*32 + (jt*16 + fr)*32 + k8s];
                s = __builtin_amdgcn_mfma_f32_16x16x32_f16(kf, qf[kk], s, 0, 0, 0);
            }
            st[jt] = s;
        }

        const bool full = (window < 0) || (j0 >= qlo + 15 - window);
        #pragma unroll
        for (int kc = 0; kc < JC; kc++) {
            #pragma unroll
            for (int jh = 0; jh < 2; jh++) {
                int jt = kc*2 + jh;
                float p[4];
                #pragma unroll
                for (int r = 0; r < 4; r++) {
                    float pv = exp2f(st[jt][r] * sc);
                    if (!full) {
                        int jg = j0 + jt*16 + g*4 + r;
                        if (jg < (qlo + fr) - window) pv = 0.f;
                    }
                    p[r] = pv;
                    lsum += pv;
                }
                half4_t ph = {(_Float16)p[0], (_Float16)p[1],
                              (_Float16)p[2], (_Float16)p[3]};
                *(half4_t*)&PsW[fr*LDP + jh*16 + g*4] = ph;
            }
            // same-wave DS ordering: write -> read -> next overwrite is safe
            half8_t pf = *(const half8_t*)&PsW[fr*LDP + k8];
            #pragma unroll
            for (int dt = 0; dt < DT; dt++) {
                half8_t vf = *(const half8_t*)&Vs[kc*DK*32 + (dt*16 + fr)*32 + k8s];
                O[dt] = __builtin_amdgcn_mfma_f32_16x16x32_f16(pf, vf, O[dt], 0, 0, 0);
            }
        }
        cur ^= 1;
    }

    lsum += __shfl_xor(lsum, 16);
    lsum += __shfl_xor(lsum, 32);
    if (g == 0) Lw[w*16 + fr] = lsum;
    float linv[4];
    #pragma unroll
    for (int r = 0; r < 4; r++)
        linv[r] = 1.f / Lw[w*16 + g*4 + r];

    if (LOUT && g == 0)
        lout[(size_t)(b*H + h)*S_ + qlo + fr] = lsum;

    #pragma unroll
    for (int r = 0; r < 4; r++) {
        _Float16* cp = ctx + (size_t)(b*S_ + qlo + g*4 + r)*CTXLD + h*DK;
        #pragma unroll
        for (int dt = 0; dt < DT; dt++)
            cp[dt*16 + fr] = (_Float16)(O[dt][r] * linv[r]);
    }
}

// ---------------------------------------------------------------------------
// Mega flash: all three branches in one 2048-block dispatch.
// T1 XCD remap: bid = (hw&7)*256 + hw>>3 (bijective). Each XCD owns 256
// logically-consecutive blocks = aligned K/V-sharing groups (~2MB < 4MB L2).
// Long on XCDs 0-3, short/medium on 4-7 (balanced within 3%).
// LDS 70.9KB -> 2 blocks/CU (launch_bounds min-waves/EU = 2).
// ---------------------------------------------------------------------------
__global__ __launch_bounds__(256, 2) void flash_mega(
    const _Float16* __restrict__ qk_s, const _Float16* __restrict__ qk_m,
    const _Float16* __restrict__ qk_l,
    const _Float16* __restrict__ vT_s, const _Float16* __restrict__ vT_m,
    const _Float16* __restrict__ vT_l,
    _Float16* __restrict__ ctxall, float* __restrict__ lbuf)
{
    __shared__ __align__(16) _Float16 lds[35328];
    __shared__ float Lw[64];

    const int hwb = blockIdx.x;
    const int bid = (hwb & 7) * 256 + (hwb >> 3);
    if (bid < 1024) {
        int qblk = bid & 31, h = (bid >> 5) & 15, b = bid >> 9;
        flash_body<64, 128, true>(lds, Lw, qk_l, vT_l, ctxall + 2048, lbuf,
                                  -1, b, h, qblk, 16);
    } else {
        int r = bid - 1024;
        int qblk = r & 31;              // heavy (qblk=0) first within group
        int h = (r >> 5) & 7;
        int z = r >> 8;                 // 0..3 = branch*2 + batch
        int br = z >> 1, b = z & 1;
        flash_body<128, 64, false>(lds, Lw, br ? qk_m : qk_s, br ? vT_m : vT_s,
                                   ctxall + (br ? 1024 : 0), nullptr,
                                   br ? 30 : 10, b, h, qblk, 8);
    }
}

// ---------------------------------------------------------------------------
// Head-averaged long-branch attention probabilities (2 heads per barrier).
// Same T2 swizzle as flash_body on the staged K tile. K-sharing blocks
// (y-varying, hw stride 16) already co-XCD (16%8==0) - no remap needed.
// ---------------------------------------------------------------------------
__global__ __launch_bounds__(256, 4) void attn_mean3(
    const _Float16* __restrict__ qk,
    const float* __restrict__ lbuf,
    float* __restrict__ attn)
{
    __shared__ __align__(16) _Float16 Ks[2 * 2 * 128 * 32];

    const int t = threadIdx.x, lane = t & 63, w = t >> 6;
    const int fr = lane & 15, g = lane >> 4, k8 = g * 8;
    const int k8s = (g ^ ((fr >> 1) & 3)) * 8;
    const int j0 = blockIdx.x * 128;
    const int irow = blockIdx.y * 64 + w * 16;
    const int b = blockIdx.z;
    const float c1 = 0.125f * 1.44269504f;
    const int srow = lane >> 2;
    const int ssw  = ((lane & 3) ^ ((srow >> 1) & 3)) * 8;

    f32x4 acc[8] = {};

    for (int hp = 0; hp < 16; hp += 2) {
        __syncthreads();
        #pragma unroll
        for (int hh = 0; hh < 2; hh++)
            #pragma unroll
            for (int kk = 0; kk < 2; kk++)
                #pragma unroll
                for (int ii = 0; ii < 2; ii++)
                    GL2LDS(&qk[(size_t)(b*S_ + j0 + w*32 + ii*16 + srow)*2048
                               + 1024 + (hp+hh)*64 + kk*32 + ssw],
                           &Ks[hh*8192 + kk*4096 + w*1024 + ii*512]);
        __syncthreads();

        #pragma unroll
        for (int hh = 0; hh < 2; hh++) {
            const int h = hp + hh;
            half8_t af[2];
            #pragma unroll
            for (int kk = 0; kk < 2; kk++)
                af[kk] = *(const half8_t*)
                    &qk[(size_t)(b*S_ + irow + fr)*2048 + h*64 + kk*32 + k8];

            float lg[4];
            #pragma unroll
            for (int r = 0; r < 4; r++)
                lg[r] = __log2f(lbuf[(size_t)(b*16 + h)*S_ + irow + g*4 + r]) + 4.0f;

            #pragma unroll
            for (int nt = 0; nt < 8; nt++) {
                f32x4 s = {};
                #pragma unroll
                for (int kk = 0; kk < 2; kk++) {
                    half8_t bf = *(const half8_t*)
                        &Ks[hh*8192 + kk*4096 + (nt*16 + fr)*32 + k8s];
                    s = __builtin_amdgcn_mfma_f32_16x16x32_f16(af[kk], bf, s, 0, 0, 0);
                }
                #pragma unroll
                for (int r = 0; r < 4; r++)
                    acc[nt][r] += exp2f(s[r] * c1 - lg[r]);
            }
        }
    }

    #pragma unroll
    for (int r = 0; r < 4; r++) {
        float* p = attn + (size_t)(b*S_ + irow + g*4 + r)*S_ + j0;
        #pragma unroll
        for (int nt = 0; nt < 8; nt++)
            p[nt*16 + fr] = acc[nt][r];
    }
}

// ---------------------------------------------------------------------------
// Residual + LayerNorm
// ---------------------------------------------------------------------------
__global__ __launch_bounds__(256) void ln_residual(
    const float* __restrict__ pre, const float* __restrict__ x,
    const float* __restrict__ gamma, const float* __restrict__ beta,
    float* __restrict__ out)
{
    __shared__ float redS[4], redQ[4];
    const int row = blockIdx.x;
    const int t = threadIdx.x;
    size_t base = (size_t)row * D_ + t * 4;

    float4 v  = *(const float4*)(pre + base);
    float4 xv = *(const float4*)(x + base);
    v.x += xv.x; v.y += xv.y; v.z += xv.z; v.w += xv.w;

    float s = v.x + v.y + v.z + v.w;
    float q = v.x*v.x + v.y*v.y + v.z*v.z + v.w*v.w;
    #pragma unroll
    for (int m = 32; m >= 1; m >>= 1) {
        s += __shfl_xor(s, m);
        q += __shfl_xor(q, m);
    }
    int wave = t >> 6;
    if ((t & 63) == 0) { redS[wave] = s; redQ[wave] = q; }
    __syncthreads();
    s = redS[0] + redS[1] + redS[2] + redS[3];
    q = redQ[0] + redQ[1] + redQ[2] + redQ[3];

    float mean = s * (1.f / D_);
    float var  = q * (1.f / D_) - mean * mean;
    float rstd = rsqrtf(var + 1e-5f);

    float4 g  = *(const float4*)(gamma + t * 4);
    float4 be = *(const float4*)(beta + t * 4);
    float4 o;
    o.x = (v.x - mean) * rstd * g.x + be.x;
    o.y = (v.y - mean) * rstd * g.y + be.y;
    o.z = (v.z - mean) * rstd * g.z + be.z;
    o.w = (v.w - mean) * rstd * g.w + be.w;
    *(float4*)(out + base) = o;
}

// ---------------------------------------------------------------------------
extern "C" void kernel_launch(void* const* d_in, const int* in_sizes, int n_in,
                              void* d_out, int out_size, void* d_ws, size_t ws_size,
                              hipStream_t stream)
{
    (void)in_sizes; (void)n_in; (void)out_size; (void)ws_size;
    const float* x      = (const float*)d_in[0];
    const float* w_in_s = (const float*)d_in[1];
    const float* b_in_s = (const float*)d_in[2];
    const float* wo_s   = (const float*)d_in[3];
    const float* bo_s   = (const float*)d_in[4];
    const float* w_in_m = (const float*)d_in[5];
    const float* b_in_m = (const float*)d_in[6];
    const float* wo_m   = (const float*)d_in[7];
    const float* bo_m   = (const float*)d_in[8];
    const float* w_in_l = (const float*)d_in[9];
    const float* b_in_l = (const float*)d_in[10];
    const float* wo_l   = (const float*)d_in[11];
    const float* bo_l   = (const float*)d_in[12];
    const float* w_comb = (const float*)d_in[13];
    const float* b_comb = (const float*)d_in[14];
    const float* gamma  = (const float*)d_in[15];
    const float* beta   = (const float*)d_in[16];

    float* out    = (float*)d_out;                 // [B,S,D]
    float* attn_o = out + (size_t)M_ * D_;         // [B,S,S]

    // Workspace (byte offsets; total ~132.3 MB <= proven-available 134.5 MB).
    // Alias lifetimes (stream order):
    //   w_comb_h+woT_s [18,26)MB dead after weff gemm -> vT_l (qkv_all writes it after)
    //   qk_m dead after flash_mega -> pre (fused gemm output)
    char* W = (char*)d_ws;
    _Float16* w_in_s_h = (_Float16*)(W);                 //  6MB
    _Float16* w_in_m_h = (_Float16*)(W + 6291456);       //  6MB
    _Float16* w_in_l_h = (_Float16*)(W + 12582912);      //  6MB
    _Float16* w_comb_h = (_Float16*)(W + 18874368);      //  6MB (-> vT_l)
    _Float16* woT_s    = (_Float16*)(W + 25165824);      //  2MB (-> vT_l tail)
    _Float16* woT_m    = (_Float16*)(W + 27262976);      //  2MB
    _Float16* woT_l    = (_Float16*)(W + 29360128);      //  2MB
    _Float16* weff     = (_Float16*)(W + 31457280);      //  6MB
    _Float16* qk_s     = (_Float16*)(W + 37748736);      // 16MB
    _Float16* qk_m     = (_Float16*)(W + 54525952);      // 16MB (-> pre fp32)
    _Float16* qk_l     = (_Float16*)(W + 71303168);      // 16MB
    _Float16* vT_s     = (_Float16*)(W + 88080384);      //  8MB
    _Float16* vT_m     = (_Float16*)(W + 96468992);      //  8MB
    _Float16* ctxall   = (_Float16*)(W + 104857600);     // 24MB [4096][3072]
    _Float16* x_h      = (_Float16*)(W + 130023424);     //  8MB
    float*    lbuf     = (float*)   (W + 138412032);     // 256KB
    float*    beff     = (float*)   (W + 138674432);     //  4KB
    _Float16* vT_l     = w_comb_h;                       // 8MB alias (see above)
    float*    pre      = (float*)qk_m;

    dim3 blk(256);
    GemmBatch nil = { nullptr, nullptr, nullptr, nullptr, nullptr };

    // ---- casts: x, w_in x3, w_comb ----
    CastArgs ca;
    ca.s[0]=x;      ca.d[0]=x_h;      ca.nb[0]=4096;
    ca.s[1]=w_in_s; ca.d[1]=w_in_s_h; ca.nb[1]=3072;
    ca.s[2]=w_in_m; ca.d[2]=w_in_m_h; ca.nb[2]=3072;
    ca.s[3]=w_in_l; ca.d[3]=w_in_l_h; ca.nb[3]=3072;
    ca.s[4]=w_comb; ca.d[4]=w_comb_h; ca.nb[4]=3072;
    cast_all<<<dim3(16384), blk, 0, stream>>>(ca);

    // ---- transpose-cast wo_* -> woT_* ----
    transpose_cast_wo<<<dim3(16, 16, 3), blk, 0, stream>>>(
        wo_s, wo_m, wo_l, woT_s, woT_m, woT_l);

    // ---- Weff_b = Wc_b @ wo_b (fp16, no bias) ----
    GemmBatch we0 = { w_comb_h + 0,    woT_s, nullptr, weff + 0,    nullptr };
    GemmBatch we1 = { w_comb_h + 1024, woT_m, nullptr, weff + 1024, nullptr };
    GemmBatch we2 = { w_comb_h + 2048, woT_l, nullptr, weff + 2048, nullptr };
    gemm_f16<3, false><<<dim3(8, 8, 3), blk, 0, stream>>>(we0, we1, we2, 3072, 1024, 3072, 1024);

    // ---- beff = b_comb + Wc . bo_cat ----
    beff_kernel<<<dim3(1024), blk, 0, stream>>>(w_comb, b_comb, bo_s, bo_m, bo_l, beff);

    // ---- all three QKV projections in one dispatch (w_comb_h now dead -> vT_l) ----
    GemmBatch qs = { x_h, w_in_s_h, b_in_s, qk_s, vT_s };
    GemmBatch qm = { x_h, w_in_m_h, b_in_m, qk_m, vT_m };
    GemmBatch ql = { x_h, w_in_l_h, b_in_l, qk_l, vT_l };
    gemm_f16<2, false><<<dim3(M_/128, 3072/128, 3), blk, 0, stream>>>(qs, qm, ql, D_, D_, 2048, D_);

    // ---- mega flash: long + short + medium in one 2048-block dispatch ----
    flash_mega<<<dim3(2048), blk, 0, stream>>>(
        qk_s, qk_m, qk_l, vT_s, vT_m, vT_l, ctxall, lbuf);

    // ---- head-averaged probabilities ----
    attn_mean3<<<dim3(S_/128, S_/64, B_), blk, 0, stream>>>(qk_l, lbuf, attn_o);

    // ---- fused (outproj+combine): pre = ctxall @ weff^T + beff ----
    GemmBatch fb = { ctxall, weff, beff, pre, nullptr };
    gemm_f16<0, false><<<dim3(M_/128, D_/128, 1), blk, 0, stream>>>(fb, nil, nil, 3072, 3072, D_, 3072);

    // ---- residual LayerNorm ----
    ln_residual<<<dim3(M_), blk, 0, stream>>>(pre, x, gamma, beta, out);
}

// Round 5
// 552.110 us; speedup vs baseline: 1.0361x; 1.0361x over previous
//
#include <hip/hip_runtime.h>
#include <hip/hip_bf16.h>
#include <math.h>

// Problem constants (fixed by reference)
#define B_ 2
#define S_ 2048
#define D_ 1024
#define M_ (B_*S_)      // 4096 rows
#define CTXLD 3072      // fused ctx row stride: [short | medium | long]

typedef _Float16 half8_t __attribute__((ext_vector_type(8)));
typedef _Float16 half4_t __attribute__((ext_vector_type(4)));
typedef float    f32x4  __attribute__((ext_vector_type(4)));

// async global->LDS: per-lane global addr; HW scatters lane i to (uniform LDS base) + i*16B
#define GL2LDS(g, l) __builtin_amdgcn_global_load_lds( \
    (const __attribute__((address_space(1))) void*)(uintptr_t)(g), \
    (__attribute__((address_space(3))) void*)(l), 16, 0, 0)

// ---------------------------------------------------------------------------
// Batched fp16-MFMA GEMM: C = A @ W^T + bias. BK=64 chunk-major.
// 128x128 tile, 4 waves. batch dim selects {b0,b1,b2}.
// MODE 0: C fp32 + bias. MODE 1: C fp16 + bias.
// MODE 2: QKV split (cols<2048 -> qk fp16 ldc; cols>=2048 -> vT transposed).
// MODE 3: C fp16, no bias (Weff prep).
// SWZ remap measured SLOWER on QKV (r3: +13us; A-refetch 3x outweighed
// W-panel L2 hits) - keep false everywhere.
// ---------------------------------------------------------------------------
struct GemmBatch {
    const _Float16* A;
    const _Float16* W;
    const float*    bias;
    void*           C;
    void*           C2;
};

template<int MODE, bool SWZ>
__global__ __launch_bounds__(256) void gemm_f16(
    GemmBatch b0, GemmBatch b1, GemmBatch b2, int lda, int ldw, int ldc, int K)
{
    __shared__ __align__(16) _Float16 As[2*128*32];
    __shared__ __align__(16) _Float16 Bs[2*128*32];

    int bx, by, bz;
    if (SWZ) {
        const int gx = gridDim.x, gy = gridDim.y;
        const int total = gx * gy * gridDim.z;
        const int lin = blockIdx.x + gx * (blockIdx.y + gy * blockIdx.z);
        const int lbid = (lin & 7) * (total >> 3) + (lin >> 3);
        bx = lbid % gx;
        const int rem = lbid / gx;
        by = rem % gy;
        bz = rem / gy;
    } else {
        bx = blockIdx.x; by = blockIdx.y; bz = blockIdx.z;
    }

    const GemmBatch G = (bz == 0) ? b0 : ((bz == 1) ? b1 : b2);

    const int t = threadIdx.x, lane = t & 63, w = t >> 6;
    const int bm = bx * 128, bn = by * 128;
    const int wm = (w >> 1) * 64, wn = (w & 1) * 64;
    const int fr = lane & 15, q8 = (lane >> 4) * 8;
    const int srow = lane >> 2, scol = (lane & 3) * 8;

    f32x4 acc[4][4] = {};

    const _Float16* Ab = G.A + (size_t)(bm + w*32 + srow) * lda + scol;
    const _Float16* Wb = G.W + (size_t)(bn + w*32 + srow) * ldw + scol;

    for (int k0 = 0; k0 < K; k0 += 64) {
        __syncthreads();
        #pragma unroll
        for (int kc = 0; kc < 2; kc++)
            #pragma unroll
            for (int ii = 0; ii < 2; ii++) {
                GL2LDS(Ab + (size_t)(ii*16)*lda + k0 + kc*32,
                       As + kc*4096 + w*1024 + ii*512);
                GL2LDS(Wb + (size_t)(ii*16)*ldw + k0 + kc*32,
                       Bs + kc*4096 + w*1024 + ii*512);
            }
        __syncthreads();
        #pragma unroll
        for (int kc = 0; kc < 2; kc++) {
            half8_t af[4], bf[4];
            #pragma unroll
            for (int mt = 0; mt < 4; mt++)
                af[mt] = *(const half8_t*)&As[kc*4096 + (wm + mt*16 + fr)*32 + q8];
            #pragma unroll
            for (int nt = 0; nt < 4; nt++)
                bf[nt] = *(const half8_t*)&Bs[kc*4096 + (wn + nt*16 + fr)*32 + q8];
            #pragma unroll
            for (int mt = 0; mt < 4; mt++)
                #pragma unroll
                for (int nt = 0; nt < 4; nt++)
                    acc[mt][nt] = __builtin_amdgcn_mfma_f32_16x16x32_f16(
                        af[mt], bf[nt], acc[mt][nt], 0, 0, 0);
        }
    }

    const int cl = lane & 15;
    const int rq = (lane >> 4) * 4;

    if (MODE == 2 && bn >= 2048) {
        #pragma unroll
        for (int mt = 0; mt < 4; mt++) {
            int row0 = bm + wm + mt*16 + rq;
            #pragma unroll
            for (int nt = 0; nt < 4; nt++) {
                int gcol = bn + wn + nt*16 + cl;
                float bv = G.bias[gcol];
                half4_t hv = {(_Float16)(acc[mt][nt][0] + bv),
                              (_Float16)(acc[mt][nt][1] + bv),
                              (_Float16)(acc[mt][nt][2] + bv),
                              (_Float16)(acc[mt][nt][3] + bv)};
                *(half4_t*)((_Float16*)G.C2 + (size_t)(gcol - 2048) * M_ + row0) = hv;
            }
        }
        return;
    }

    #pragma unroll
    for (int mt = 0; mt < 4; mt++) {
        #pragma unroll
        for (int r = 0; r < 4; r++) {
            size_t grow = (size_t)(bm + wm + mt*16 + rq + r);
            #pragma unroll
            for (int nt = 0; nt < 4; nt++) {
                int gcol = bn + wn + nt*16 + cl;
                float v = acc[mt][nt][r] + ((MODE == 3) ? 0.f : G.bias[gcol]);
                if (MODE == 0)
                    ((float*)G.C)[grow * ldc + gcol] = v;
                else
                    ((_Float16*)G.C)[grow * ldc + gcol] = (_Float16)v;
            }
        }
    }
}

// ---------------------------------------------------------------------------
// Fused fp32 -> fp16 cast (5 tensors: x, w_in x3, w_comb).
// ---------------------------------------------------------------------------
struct CastArgs {
    const float* s[5];
    _Float16*    d[5];
    int          nb[5];
};

__global__ __launch_bounds__(256) void cast_all(CastArgs a)
{
    int off = blockIdx.x;
    int seg = 0;
    while (seg < 4 && off >= a.nb[seg]) { off -= a.nb[seg]; seg++; }
    int i = off * 256 + threadIdx.x;
    float4 v = ((const float4*)a.s[seg])[i];
    half4_t h = {(_Float16)v.x, (_Float16)v.y, (_Float16)v.z, (_Float16)v.w};
    ((half4_t*)a.d[seg])[i] = h;
}

// ---------------------------------------------------------------------------
// Transposing cast for wo_* : in fp32 [1024 d][1024 e] -> out fp16 [e][d].
// ---------------------------------------------------------------------------
__global__ __launch_bounds__(256) void transpose_cast_wo(
    const float* s0, const float* s1, const float* s2,
    _Float16* d0, _Float16* d1, _Float16* d2)
{
    __shared__ float T[64][68];
    const float* src = blockIdx.z == 0 ? s0 : (blockIdx.z == 1 ? s1 : s2);
    _Float16*    dst = blockIdx.z == 0 ? d0 : (blockIdx.z == 1 ? d1 : d2);
    const int db = blockIdx.x * 64;
    const int eb = blockIdx.y * 64;
    const int r = threadIdx.x >> 4;
    const int c = (threadIdx.x & 15) * 4;

    #pragma unroll
    for (int rr = 0; rr < 4; rr++) {
        float4 v = *(const float4*)&src[(size_t)(db + rr*16 + r)*1024 + eb + c];
        T[rr*16 + r][c+0] = v.x; T[rr*16 + r][c+1] = v.y;
        T[rr*16 + r][c+2] = v.z; T[rr*16 + r][c+3] = v.w;
    }
    __syncthreads();
    #pragma unroll
    for (int rr = 0; rr < 4; rr++) {
        int e = rr*16 + r;
        half4_t hv = {(_Float16)T[c+0][e], (_Float16)T[c+1][e],
                      (_Float16)T[c+2][e], (_Float16)T[c+3][e]};
        *(half4_t*)&dst[(size_t)(eb + e)*1024 + db + c] = hv;
    }
}

// ---------------------------------------------------------------------------
// beff[n] = b_comb[n] + sum_d bo_s[d] Wc[n][d] + bo_m[d] Wc[n][1024+d] + bo_l[d] Wc[n][2048+d]
// ---------------------------------------------------------------------------
__global__ __launch_bounds__(256) void beff_kernel(
    const float* __restrict__ w_comb, const float* __restrict__ b_comb,
    const float* __restrict__ bo_s, const float* __restrict__ bo_m,
    const float* __restrict__ bo_l, float* __restrict__ beff)
{
    __shared__ float red[4];
    const int n = blockIdx.x, t = threadIdx.x;
    float s = 0.f;
    for (int d = t; d < 1024; d += 256)
        s += w_comb[(size_t)n*3072 + d]        * bo_s[d]
           + w_comb[(size_t)n*3072 + 1024 + d] * bo_m[d]
           + w_comb[(size_t)n*3072 + 2048 + d] * bo_l[d];
    #pragma unroll
    for (int m = 32; m >= 1; m >>= 1) s += __shfl_xor(s, m);
    if ((t & 63) == 0) red[t >> 6] = s;
    __syncthreads();
    if (t == 0) beff[n] = b_comb[n] + red[0] + red[1] + red[2] + red[3];
}

// ---------------------------------------------------------------------------
// Flash attention body — r3 single-buffered structure (r4's explicit dbuf
// regressed: occupancy 30->18% outweighed pipeline gain; reverted).
// LDS partition (halfs): Ks [0, DK*BJ) | Vs [DK*BJ, 2*DK*BJ) | Ps (P patch).
// DK*BJ = 8192 both instantiations -> 37.9KB -> 4 blocks/CU; implicit
// inter-block overlap hides the stage drain (m114 mechanism).
//
// T2 bank-conflict swizzle (r2): XOR 16B slot with (row>>1)&3 via
// pre-swizzled global source + swizzled read (BANK_CONFLICT 2.2e7->4.9e6).
// T5 (r5): s_setprio(1) around MFMA clusters - co-resident independent
// blocks at different phases (m191-positive regime).
// ---------------------------------------------------------------------------
template<int DK, int BJ, bool LOUT>
__device__ __forceinline__ void flash_body(
    _Float16* lds, float* Lw,
    const _Float16* __restrict__ qk, const _Float16* __restrict__ vT,
    _Float16* __restrict__ ctx, float* __restrict__ lout,
    int window, int b, int h, int qblk, int H)
{
    constexpr int KS  = DK / 32;     // k-chunks
    constexpr int DT  = DK / 16;     // PV d-tiles
    constexpr int JT  = BJ / 16;     // j-subtiles per round
    constexpr int JC  = BJ / 32;     // j-chunks per round (PV kc count)
    constexpr int LDP = 40;

    _Float16* Ks = lds;
    _Float16* Vs = lds + DK*BJ;
    _Float16* Ps = lds + 2*DK*BJ;

    const int t = threadIdx.x, lane = t & 63, w = t >> 6;
    const int fr = lane & 15, g = lane >> 4, k8 = g * 8;
    // swizzled LDS fragment slot: slot g holds global chunk g^((row>>1)&3)
    const int k8s = (g ^ ((fr >> 1) & 3)) * 8;
    const int blkQ = qblk * 64;
    const int qlo  = blkQ + w * 16;

    const float sc = ((DK == 128) ? 0.08838834764831845f : 0.125f) * 1.44269504f;

    _Float16* PsW = Ps + w * 16 * LDP;
    const int srow = lane >> 2;
    // stage-side inverse swizzle of the global source chunk
    const int ssw  = ((lane & 3) ^ ((srow >> 1) & 3)) * 8;

    half8_t qf[KS];
    #pragma unroll
    for (int kk = 0; kk < KS; kk++)
        qf[kk] = *(const half8_t*)&qk[(size_t)(b*S_ + qlo + fr)*2048 + h*DK + kk*32 + k8];

    f32x4 O[DT] = {};
    float lsum = 0.f;

    for (int j0 = 0; j0 < S_; j0 += BJ) {
        if (window >= 0 && j0 + BJ - 1 < blkQ - window) continue;
        __syncthreads();

        // stage K: [kchunk][BJ rows][32]; wave w rows w*(BJ/4)+ii*16+srow
        #pragma unroll
        for (int kk = 0; kk < KS; kk++)
            #pragma unroll
            for (int ii = 0; ii < BJ/64; ii++)
                GL2LDS(&qk[(size_t)(b*S_ + j0 + w*(BJ/4) + ii*16 + srow)*2048
                           + 1024 + h*DK + kk*32 + ssw],
                       &Ks[kk*BJ*32 + w*(BJ/4)*32 + ii*512]);
        // stage vT: [jchunk][DK rows][32]; wave w d-rows w*(DK/4)+ii*16+srow
        #pragma unroll
        for (int jc = 0; jc < JC; jc++)
            #pragma unroll
            for (int ii = 0; ii < DK/64; ii++)
                GL2LDS(&vT[(size_t)(h*DK + w*(DK/4) + ii*16 + srow)*M_
                           + b*S_ + j0 + jc*32 + ssw],
                       &Vs[jc*DK*32 + w*(DK/4)*32 + ii*512]);
        __syncthreads();

        f32x4 st[JT];
        __builtin_amdgcn_s_setprio(1);
        #pragma unroll
        for (int jt = 0; jt < JT; jt++) {
            f32x4 s = {};
            #pragma unroll
            for (int kk = 0; kk < KS; kk++) {
                half8_t kf = *(const half8_t*)&Ks[kk*BJ*32 + (jt*16 + fr)*32 + k8s];
                s = __builtin_amdgcn_mfma_f32_16x16x32_f16(kf, qf[kk], s, 0, 0, 0);
            }
            st[jt] = s;
        }
        __builtin_amdgcn_s_setprio(0);

        const bool full = (window < 0) || (j0 >= qlo + 15 - window);
        #pragma unroll
        for (int kc = 0; kc < JC; kc++) {
            #pragma unroll
            for (int jh = 0; jh < 2; jh++) {
                int jt = kc*2 + jh;
                float p[4];
                #pragma unroll
                for (int r = 0; r < 4; r++) {
                    float pv = exp2f(st[jt][r] * sc);
                    if (!full) {
                        int jg = j0 + jt*16 + g*4 + r;
                        if (jg < (qlo + fr) - window) pv = 0.f;
                    }
                    p[r] = pv;
                    lsum += pv;
                }
                half4_t ph = {(_Float16)p[0], (_Float16)p[1],
                              (_Float16)p[2], (_Float16)p[3]};
                *(half4_t*)&PsW[fr*LDP + jh*16 + g*4] = ph;
            }
            // same-wave DS ordering: write -> read -> next overwrite is safe
            half8_t pf = *(const half8_t*)&PsW[fr*LDP + k8];
            __builtin_amdgcn_s_setprio(1);
            #pragma unroll
            for (int dt = 0; dt < DT; dt++) {
                half8_t vf = *(const half8_t*)&Vs[kc*DK*32 + (dt*16 + fr)*32 + k8s];
                O[dt] = __builtin_amdgcn_mfma_f32_16x16x32_f16(pf, vf, O[dt], 0, 0, 0);
            }
            __builtin_amdgcn_s_setprio(0);
        }
    }

    lsum += __shfl_xor(lsum, 16);
    lsum += __shfl_xor(lsum, 32);
    if (g == 0) Lw[w*16 + fr] = lsum;
    float linv[4];
    #pragma unroll
    for (int r = 0; r < 4; r++)
        linv[r] = 1.f / Lw[w*16 + g*4 + r];

    if (LOUT && g == 0)
        lout[(size_t)(b*H + h)*S_ + qlo + fr] = lsum;

    #pragma unroll
    for (int r = 0; r < 4; r++) {
        _Float16* cp = ctx + (size_t)(b*S_ + qlo + g*4 + r)*CTXLD + h*DK;
        #pragma unroll
        for (int dt = 0; dt < DT; dt++)
            cp[dt*16 + fr] = (_Float16)(O[dt][r] * linv[r]);
    }
}

// ---------------------------------------------------------------------------
// Mega flash: all three branches in one 2048-block dispatch.
// T1 XCD remap (r3): bid = (hw&7)*256 + hw>>3 (bijective). Each XCD owns
// 256 logically-consecutive blocks = aligned K/V-sharing groups (~2MB < 4MB
// L2). FETCH 364MB -> 44MB measured. Long on XCDs 0-3, s/m on 4-7.
// s/m qblk = r&31 (heavy qblk=0 first within each group).
// ---------------------------------------------------------------------------
__global__ __launch_bounds__(256, 4) void flash_mega(
    const _Float16* __restrict__ qk_s, const _Float16* __restrict__ qk_m,
    const _Float16* __restrict__ qk_l,
    const _Float16* __restrict__ vT_s, const _Float16* __restrict__ vT_m,
    const _Float16* __restrict__ vT_l,
    _Float16* __restrict__ ctxall, float* __restrict__ lbuf)
{
    __shared__ __align__(16) _Float16 lds[18944];
    __shared__ float Lw[64];

    const int hwb = blockIdx.x;
    const int bid = (hwb & 7) * 256 + (hwb >> 3);
    if (bid < 1024) {
        int qblk = bid & 31, h = (bid >> 5) & 15, b = bid >> 9;
        flash_body<64, 128, true>(lds, Lw, qk_l, vT_l, ctxall + 2048, lbuf,
                                  -1, b, h, qblk, 16);
    } else {
        int r = bid - 1024;
        int qblk = r & 31;              // heavy (qblk=0) first within group
        int h = (r >> 5) & 7;
        int z = r >> 8;                 // 0..3 = branch*2 + batch
        int br = z >> 1, b = z & 1;
        flash_body<128, 64, false>(lds, Lw, br ? qk_m : qk_s, br ? vT_m : vT_s,
                                   ctxall + (br ? 1024 : 0), nullptr,
                                   br ? 30 : 10, b, h, qblk, 8);
    }
}

// ---------------------------------------------------------------------------
// Head-averaged long-branch attention probabilities (2 heads per barrier).
// Same T2 swizzle as flash_body on the staged K tile. K-sharing blocks
// (y-varying, hw stride 16) already co-XCD (16%8==0) - no remap needed.
// ---------------------------------------------------------------------------
__global__ __launch_bounds__(256, 4) void attn_mean3(
    const _Float16* __restrict__ qk,
    const float* __restrict__ lbuf,
    float* __restrict__ attn)
{
    __shared__ __align__(16) _Float16 Ks[2 * 2 * 128 * 32];

    const int t = threadIdx.x, lane = t & 63, w = t >> 6;
    const int fr = lane & 15, g = lane >> 4, k8 = g * 8;
    const int k8s = (g ^ ((fr >> 1) & 3)) * 8;
    const int j0 = blockIdx.x * 128;
    const int irow = blockIdx.y * 64 + w * 16;
    const int b = blockIdx.z;
    const float c1 = 0.125f * 1.44269504f;
    const int srow = lane >> 2;
    const int ssw  = ((lane & 3) ^ ((srow >> 1) & 3)) * 8;

    f32x4 acc[8] = {};

    for (int hp = 0; hp < 16; hp += 2) {
        __syncthreads();
        #pragma unroll
        for (int hh = 0; hh < 2; hh++)
            #pragma unroll
            for (int kk = 0; kk < 2; kk++)
                #pragma unroll
                for (int ii = 0; ii < 2; ii++)
                    GL2LDS(&qk[(size_t)(b*S_ + j0 + w*32 + ii*16 + srow)*2048
                               + 1024 + (hp+hh)*64 + kk*32 + ssw],
                           &Ks[hh*8192 + kk*4096 + w*1024 + ii*512]);
        __syncthreads();

        #pragma unroll
        for (int hh = 0; hh < 2; hh++) {
            const int h = hp + hh;
            half8_t af[2];
            #pragma unroll
            for (int kk = 0; kk < 2; kk++)
                af[kk] = *(const half8_t*)
                    &qk[(size_t)(b*S_ + irow + fr)*2048 + h*64 + kk*32 + k8];

            float lg[4];
            #pragma unroll
            for (int r = 0; r < 4; r++)
                lg[r] = __log2f(lbuf[(size_t)(b*16 + h)*S_ + irow + g*4 + r]) + 4.0f;

            #pragma unroll
            for (int nt = 0; nt < 8; nt++) {
                f32x4 s = {};
                #pragma unroll
                for (int kk = 0; kk < 2; kk++) {
                    half8_t bf = *(const half8_t*)
                        &Ks[hh*8192 + kk*4096 + (nt*16 + fr)*32 + k8s];
                    s = __builtin_amdgcn_mfma_f32_16x16x32_f16(af[kk], bf, s, 0, 0, 0);
                }
                #pragma unroll
                for (int r = 0; r < 4; r++)
                    acc[nt][r] += exp2f(s[r] * c1 - lg[r]);
            }
        }
    }

    #pragma unroll
    for (int r = 0; r < 4; r++) {
        float* p = attn + (size_t)(b*S_ + irow + g*4 + r)*S_ + j0;
        #pragma unroll
        for (int nt = 0; nt < 8; nt++)
            p[nt*16 + fr] = acc[nt][r];
    }
}

// ---------------------------------------------------------------------------
// Residual + LayerNorm
// ---------------------------------------------------------------------------
__global__ __launch_bounds__(256) void ln_residual(
    const float* __restrict__ pre, const float* __restrict__ x,
    const float* __restrict__ gamma, const float* __restrict__ beta,
    float* __restrict__ out)
{
    __shared__ float redS[4], redQ[4];
    const int row = blockIdx.x;
    const int t = threadIdx.x;
    size_t base = (size_t)row * D_ + t * 4;

    float4 v  = *(const float4*)(pre + base);
    float4 xv = *(const float4*)(x + base);
    v.x += xv.x; v.y += xv.y; v.z += xv.z; v.w += xv.w;

    float s = v.x + v.y + v.z + v.w;
    float q = v.x*v.x + v.y*v.y + v.z*v.z + v.w*v.w;
    #pragma unroll
    for (int m = 32; m >= 1; m >>= 1) {
        s += __shfl_xor(s, m);
        q += __shfl_xor(q, m);
    }
    int wave = t >> 6;
    if ((t & 63) == 0) { redS[wave] = s; redQ[wave] = q; }
    __syncthreads();
    s = redS[0] + redS[1] + redS[2] + redS[3];
    q = redQ[0] + redQ[1] + redQ[2] + redQ[3];

    float mean = s * (1.f / D_);
    float var  = q * (1.f / D_) - mean * mean;
    float rstd = rsqrtf(var + 1e-5f);

    float4 g  = *(const float4*)(gamma + t * 4);
    float4 be = *(const float4*)(beta + t * 4);
    float4 o;
    o.x = (v.x - mean) * rstd * g.x + be.x;
    o.y = (v.y - mean) * rstd * g.y + be.y;
    o.z = (v.z - mean) * rstd * g.z + be.z;
    o.w = (v.w - mean) * rstd * g.w + be.w;
    *(float4*)(out + base) = o;
}

// ---------------------------------------------------------------------------
extern "C" void kernel_launch(void* const* d_in, const int* in_sizes, int n_in,
                              void* d_out, int out_size, void* d_ws, size_t ws_size,
                              hipStream_t stream)
{
    (void)in_sizes; (void)n_in; (void)out_size; (void)ws_size;
    const float* x      = (const float*)d_in[0];
    const float* w_in_s = (const float*)d_in[1];
    const float* b_in_s = (const float*)d_in[2];
    const float* wo_s   = (const float*)d_in[3];
    const float* bo_s   = (const float*)d_in[4];
    const float* w_in_m = (const float*)d_in[5];
    const float* b_in_m = (const float*)d_in[6];
    const float* wo_m   = (const float*)d_in[7];
    const float* bo_m   = (const float*)d_in[8];
    const float* w_in_l = (const float*)d_in[9];
    const float* b_in_l = (const float*)d_in[10];
    const float* wo_l   = (const float*)d_in[11];
    const float* bo_l   = (const float*)d_in[12];
    const float* w_comb = (const float*)d_in[13];
    const float* b_comb = (const float*)d_in[14];
    const float* gamma  = (const float*)d_in[15];
    const float* beta   = (const float*)d_in[16];

    float* out    = (float*)d_out;                 // [B,S,D]
    float* attn_o = out + (size_t)M_ * D_;         // [B,S,S]

    // Workspace (byte offsets; total ~132.3 MB <= proven-available 134.5 MB).
    // Alias lifetimes (stream order):
    //   w_comb_h+woT_s [18,26)MB dead after weff gemm -> vT_l (qkv_all writes it after)
    //   qk_m dead after flash_mega -> pre (fused gemm output)
    char* W = (char*)d_ws;
    _Float16* w_in_s_h = (_Float16*)(W);                 //  6MB
    _Float16* w_in_m_h = (_Float16*)(W + 6291456);       //  6MB
    _Float16* w_in_l_h = (_Float16*)(W + 12582912);      //  6MB
    _Float16* w_comb_h = (_Float16*)(W + 18874368);      //  6MB (-> vT_l)
    _Float16* woT_s    = (_Float16*)(W + 25165824);      //  2MB (-> vT_l tail)
    _Float16* woT_m    = (_Float16*)(W + 27262976);      //  2MB
    _Float16* woT_l    = (_Float16*)(W + 29360128);      //  2MB
    _Float16* weff     = (_Float16*)(W + 31457280);      //  6MB
    _Float16* qk_s     = (_Float16*)(W + 37748736);      // 16MB
    _Float16* qk_m     = (_Float16*)(W + 54525952);      // 16MB (-> pre fp32)
    _Float16* qk_l     = (_Float16*)(W + 71303168);      // 16MB
    _Float16* vT_s     = (_Float16*)(W + 88080384);      //  8MB
    _Float16* vT_m     = (_Float16*)(W + 96468992);      //  8MB
    _Float16* ctxall   = (_Float16*)(W + 104857600);     // 24MB [4096][3072]
    _Float16* x_h      = (_Float16*)(W + 130023424);     //  8MB
    float*    lbuf     = (float*)   (W + 138412032);     // 256KB
    float*    beff     = (float*)   (W + 138674432);     //  4KB
    _Float16* vT_l     = w_comb_h;                       // 8MB alias (see above)
    float*    pre      = (float*)qk_m;

    dim3 blk(256);
    GemmBatch nil = { nullptr, nullptr, nullptr, nullptr, nullptr };

    // ---- casts: x, w_in x3, w_comb ----
    CastArgs ca;
    ca.s[0]=x;      ca.d[0]=x_h;      ca.nb[0]=4096;
    ca.s[1]=w_in_s; ca.d[1]=w_in_s_h; ca.nb[1]=3072;
    ca.s[2]=w_in_m; ca.d[2]=w_in_m_h; ca.nb[2]=3072;
    ca.s[3]=w_in_l; ca.d[3]=w_in_l_h; ca.nb[3]=3072;
    ca.s[4]=w_comb; ca.d[4]=w_comb_h; ca.nb[4]=3072;
    cast_all<<<dim3(16384), blk, 0, stream>>>(ca);

    // ---- transpose-cast wo_* -> woT_* ----
    transpose_cast_wo<<<dim3(16, 16, 3), blk, 0, stream>>>(
        wo_s, wo_m, wo_l, woT_s, woT_m, woT_l);

    // ---- Weff_b = Wc_b @ wo_b (fp16, no bias) ----
    GemmBatch we0 = { w_comb_h + 0,    woT_s, nullptr, weff + 0,    nullptr };
    GemmBatch we1 = { w_comb_h + 1024, woT_m, nullptr, weff + 1024, nullptr };
    GemmBatch we2 = { w_comb_h + 2048, woT_l, nullptr, weff + 2048, nullptr };
    gemm_f16<3, false><<<dim3(8, 8, 3), blk, 0, stream>>>(we0, we1, we2, 3072, 1024, 3072, 1024);

    // ---- beff = b_comb + Wc . bo_cat ----
    beff_kernel<<<dim3(1024), blk, 0, stream>>>(w_comb, b_comb, bo_s, bo_m, bo_l, beff);

    // ---- all three QKV projections in one dispatch (w_comb_h now dead -> vT_l) ----
    GemmBatch qs = { x_h, w_in_s_h, b_in_s, qk_s, vT_s };
    GemmBatch qm = { x_h, w_in_m_h, b_in_m, qk_m, vT_m };
    GemmBatch ql = { x_h, w_in_l_h, b_in_l, qk_l, vT_l };
    gemm_f16<2, false><<<dim3(M_/128, 3072/128, 3), blk, 0, stream>>>(qs, qm, ql, D_, D_, 2048, D_);

    // ---- mega flash: long + short + medium in one 2048-block dispatch ----
    flash_mega<<<dim3(2048), blk, 0, stream>>>(
        qk_s, qk_m, qk_l, vT_s, vT_m, vT_l, ctxall, lbuf);

    // ---- head-averaged probabilities ----
    attn_mean3<<<dim3(S_/128, S_/64, B_), blk, 0, stream>>>(qk_l, lbuf, attn_o);

    // ---- fused (outproj+combine): pre = ctxall @ weff^T + beff ----
    GemmBatch fb = { ctxall, weff, beff, pre, nullptr };
    gemm_f16<0, false><<<dim3(M_/128, D_/128, 1), blk, 0, stream>>>(fb, nil, nil, 3072, 3072, D_, 3072);

    // ---- residual LayerNorm ----
    ln_residual<<<dim3(M_), blk, 0, stream>>>(pre, x, gamma, beta, out);
}

// Round 6
// 538.407 us; speedup vs baseline: 1.0625x; 1.0255x over previous
//
#include <hip/hip_runtime.h>
#include <hip/hip_bf16.h>
#include <math.h>

// Problem constants (fixed by reference)
#define B_ 2
#define S_ 2048
#define D_ 1024
#define M_ (B_*S_)      // 4096 rows
#define CTXLD 3072      // fused ctx row stride: [short | medium | long]

typedef _Float16 half8_t __attribute__((ext_vector_type(8)));
typedef _Float16 half4_t __attribute__((ext_vector_type(4)));
typedef float    f32x4  __attribute__((ext_vector_type(4)));

// async global->LDS: per-lane global addr; HW scatters lane i to (uniform LDS base) + i*16B
#define GL2LDS(g, l) __builtin_amdgcn_global_load_lds( \
    (const __attribute__((address_space(1))) void*)(uintptr_t)(g), \
    (__attribute__((address_space(3))) void*)(l), 16, 0, 0)

// ---------------------------------------------------------------------------
// Batched fp16-MFMA GEMM: C = A @ W^T + bias. BK=64 chunk-major.
// 128xNB tile (NB in {128,64}), 4 waves. batch dim selects {b0,b1,b2}.
// MODE 0: C fp32 + bias. MODE 1: C fp16 + bias.
// MODE 2: QKV split (cols<2048 -> qk fp16 ldc; cols>=2048 -> vT transposed).
// MODE 3: C fp16, no bias (Weff prep).
// NB=64 for small-N dispatches (outproj N=1024 was 256 blocks = 1/CU ->
// zero inter-block overlap, fully exposed stage drain; 512 blocks = 2/CU).
// XCD-SWZ removed: r3 measured it SLOWER on QKV (+13us).
// ---------------------------------------------------------------------------
struct GemmBatch {
    const _Float16* A;
    const _Float16* W;
    const float*    bias;
    void*           C;
    void*           C2;
};

template<int MODE, int NB>
__global__ __launch_bounds__(256) void gemm_f16(
    GemmBatch b0, GemmBatch b1, GemmBatch b2, int lda, int ldw, int ldc, int K)
{
    constexpr int NT = NB / 32;          // per-wave n-subtiles
    __shared__ __align__(16) _Float16 As[2*128*32];
    __shared__ __align__(16) _Float16 Bs[2*NB*32];

    const GemmBatch G = (blockIdx.z == 0) ? b0 : ((blockIdx.z == 1) ? b1 : b2);

    const int t = threadIdx.x, lane = t & 63, w = t >> 6;
    const int bm = blockIdx.x * 128, bn = blockIdx.y * NB;
    const int wm = (w >> 1) * 64, wn = (w & 1) * (NB/2);
    const int fr = lane & 15, q8 = (lane >> 4) * 8;
    const int srow = lane >> 2, scol = (lane & 3) * 8;

    f32x4 acc[4][NT] = {};

    const _Float16* Ab = G.A + (size_t)(bm + w*32 + srow) * lda + scol;
    const _Float16* Wb = G.W + (size_t)(bn + w*(NB/4) + srow) * ldw + scol;

    for (int k0 = 0; k0 < K; k0 += 64) {
        __syncthreads();
        #pragma unroll
        for (int kc = 0; kc < 2; kc++) {
            #pragma unroll
            for (int ii = 0; ii < 2; ii++)
                GL2LDS(Ab + (size_t)(ii*16)*lda + k0 + kc*32,
                       As + kc*4096 + w*1024 + ii*512);
            #pragma unroll
            for (int ii = 0; ii < NB/64; ii++)
                GL2LDS(Wb + (size_t)(ii*16)*ldw + k0 + kc*32,
                       Bs + kc*NB*32 + w*(NB/4)*32 + ii*512);
        }
        __syncthreads();
        #pragma unroll
        for (int kc = 0; kc < 2; kc++) {
            half8_t af[4], bf[NT];
            #pragma unroll
            for (int mt = 0; mt < 4; mt++)
                af[mt] = *(const half8_t*)&As[kc*4096 + (wm + mt*16 + fr)*32 + q8];
            #pragma unroll
            for (int nt = 0; nt < NT; nt++)
                bf[nt] = *(const half8_t*)&Bs[kc*NB*32 + (wn + nt*16 + fr)*32 + q8];
            #pragma unroll
            for (int mt = 0; mt < 4; mt++)
                #pragma unroll
                for (int nt = 0; nt < NT; nt++)
                    acc[mt][nt] = __builtin_amdgcn_mfma_f32_16x16x32_f16(
                        af[mt], bf[nt], acc[mt][nt], 0, 0, 0);
        }
    }

    const int cl = lane & 15;
    const int rq = (lane >> 4) * 4;

    if (MODE == 2 && bn >= 2048) {
        #pragma unroll
        for (int mt = 0; mt < 4; mt++) {
            int row0 = bm + wm + mt*16 + rq;
            #pragma unroll
            for (int nt = 0; nt < NT; nt++) {
                int gcol = bn + wn + nt*16 + cl;
                float bv = G.bias[gcol];
                half4_t hv = {(_Float16)(acc[mt][nt][0] + bv),
                              (_Float16)(acc[mt][nt][1] + bv),
                              (_Float16)(acc[mt][nt][2] + bv),
                              (_Float16)(acc[mt][nt][3] + bv)};
                *(half4_t*)((_Float16*)G.C2 + (size_t)(gcol - 2048) * M_ + row0) = hv;
            }
        }
        return;
    }

    #pragma unroll
    for (int mt = 0; mt < 4; mt++) {
        #pragma unroll
        for (int r = 0; r < 4; r++) {
            size_t grow = (size_t)(bm + wm + mt*16 + rq + r);
            #pragma unroll
            for (int nt = 0; nt < NT; nt++) {
                int gcol = bn + wn + nt*16 + cl;
                float v = acc[mt][nt][r] + ((MODE == 3) ? 0.f : G.bias[gcol]);
                if (MODE == 0)
                    ((float*)G.C)[grow * ldc + gcol] = v;
                else
                    ((_Float16*)G.C)[grow * ldc + gcol] = (_Float16)v;
            }
        }
    }
}

// ---------------------------------------------------------------------------
// Fused fp32 -> fp16 cast (5 tensors: x, w_in x3, w_comb).
// ---------------------------------------------------------------------------
struct CastArgs {
    const float* s[5];
    _Float16*    d[5];
    int          nb[5];
};

__global__ __launch_bounds__(256) void cast_all(CastArgs a)
{
    int off = blockIdx.x;
    int seg = 0;
    while (seg < 4 && off >= a.nb[seg]) { off -= a.nb[seg]; seg++; }
    int i = off * 256 + threadIdx.x;
    float4 v = ((const float4*)a.s[seg])[i];
    half4_t h = {(_Float16)v.x, (_Float16)v.y, (_Float16)v.z, (_Float16)v.w};
    ((half4_t*)a.d[seg])[i] = h;
}

// ---------------------------------------------------------------------------
// Transposing cast for wo_* : in fp32 [1024 d][1024 e] -> out fp16 [e][d].
// ---------------------------------------------------------------------------
__global__ __launch_bounds__(256) void transpose_cast_wo(
    const float* s0, const float* s1, const float* s2,
    _Float16* d0, _Float16* d1, _Float16* d2)
{
    __shared__ float T[64][68];
    const float* src = blockIdx.z == 0 ? s0 : (blockIdx.z == 1 ? s1 : s2);
    _Float16*    dst = blockIdx.z == 0 ? d0 : (blockIdx.z == 1 ? d1 : d2);
    const int db = blockIdx.x * 64;
    const int eb = blockIdx.y * 64;
    const int r = threadIdx.x >> 4;
    const int c = (threadIdx.x & 15) * 4;

    #pragma unroll
    for (int rr = 0; rr < 4; rr++) {
        float4 v = *(const float4*)&src[(size_t)(db + rr*16 + r)*1024 + eb + c];
        T[rr*16 + r][c+0] = v.x; T[rr*16 + r][c+1] = v.y;
        T[rr*16 + r][c+2] = v.z; T[rr*16 + r][c+3] = v.w;
    }
    __syncthreads();
    #pragma unroll
    for (int rr = 0; rr < 4; rr++) {
        int e = rr*16 + r;
        half4_t hv = {(_Float16)T[c+0][e], (_Float16)T[c+1][e],
                      (_Float16)T[c+2][e], (_Float16)T[c+3][e]};
        *(half4_t*)&dst[(size_t)(eb + e)*1024 + db + c] = hv;
    }
}

// ---------------------------------------------------------------------------
// beff[n] = b_comb[n] + sum_d bo_s[d] Wc[n][d] + bo_m[d] Wc[n][1024+d] + bo_l[d] Wc[n][2048+d]
// ---------------------------------------------------------------------------
__global__ __launch_bounds__(256) void beff_kernel(
    const float* __restrict__ w_comb, const float* __restrict__ b_comb,
    const float* __restrict__ bo_s, const float* __restrict__ bo_m,
    const float* __restrict__ bo_l, float* __restrict__ beff)
{
    __shared__ float red[4];
    const int n = blockIdx.x, t = threadIdx.x;
    float s = 0.f;
    for (int d = t; d < 1024; d += 256)
        s += w_comb[(size_t)n*3072 + d]        * bo_s[d]
           + w_comb[(size_t)n*3072 + 1024 + d] * bo_m[d]
           + w_comb[(size_t)n*3072 + 2048 + d] * bo_l[d];
    #pragma unroll
    for (int m = 32; m >= 1; m >>= 1) s += __shfl_xor(s, m);
    if ((t & 63) == 0) red[t >> 6] = s;
    __syncthreads();
    if (t == 0) beff[n] = b_comb[n] + red[0] + red[1] + red[2] + red[3];
}

// ---------------------------------------------------------------------------
// Flash attention body — r3-proven single-buffered structure.
// (r4 explicit dbuf regressed: occupancy 30->18%. r5 setprio regressed:
// +9.6us — 4 waves/block are barrier-locked = m190 lockstep-null regime,
// and boosting them starves other blocks' staging. Both reverted.)
// LDS partition (halfs): Ks [0, DK*BJ) | Vs [DK*BJ, 2*DK*BJ) | Ps (P patch).
// DK*BJ = 8192 both instantiations -> 37.9KB -> 4 blocks/CU; implicit
// inter-block overlap hides the stage drain (m114 mechanism).
//
// T2 bank-conflict swizzle (r2): XOR 16B slot with (row>>1)&3 via
// pre-swizzled global source + swizzled read (BANK_CONFLICT 2.2e7->4.9e6).
// ---------------------------------------------------------------------------
template<int DK, int BJ, bool LOUT>
__device__ __forceinline__ void flash_body(
    _Float16* lds, float* Lw,
    const _Float16* __restrict__ qk, const _Float16* __restrict__ vT,
    _Float16* __restrict__ ctx, float* __restrict__ lout,
    int window, int b, int h, int qblk, int H)
{
    constexpr int KS  = DK / 32;     // k-chunks
    constexpr int DT  = DK / 16;     // PV d-tiles
    constexpr int JT  = BJ / 16;     // j-subtiles per round
    constexpr int JC  = BJ / 32;     // j-chunks per round (PV kc count)
    constexpr int LDP = 40;

    _Float16* Ks = lds;
    _Float16* Vs = lds + DK*BJ;
    _Float16* Ps = lds + 2*DK*BJ;

    const int t = threadIdx.x, lane = t & 63, w = t >> 6;
    const int fr = lane & 15, g = lane >> 4, k8 = g * 8;
    // swizzled LDS fragment slot: slot g holds global chunk g^((row>>1)&3)
    const int k8s = (g ^ ((fr >> 1) & 3)) * 8;
    const int blkQ = qblk * 64;
    const int qlo  = blkQ + w * 16;

    const float sc = ((DK == 128) ? 0.08838834764831845f : 0.125f) * 1.44269504f;

    _Float16* PsW = Ps + w * 16 * LDP;
    const int srow = lane >> 2;
    // stage-side inverse swizzle of the global source chunk
    const int ssw  = ((lane & 3) ^ ((srow >> 1) & 3)) * 8;

    half8_t qf[KS];
    #pragma unroll
    for (int kk = 0; kk < KS; kk++)
        qf[kk] = *(const half8_t*)&qk[(size_t)(b*S_ + qlo + fr)*2048 + h*DK + kk*32 + k8];

    f32x4 O[DT] = {};
    float lsum = 0.f;

    for (int j0 = 0; j0 < S_; j0 += BJ) {
        if (window >= 0 && j0 + BJ - 1 < blkQ - window) continue;
        __syncthreads();

        // stage K: [kchunk][BJ rows][32]; wave w rows w*(BJ/4)+ii*16+srow
        #pragma unroll
        for (int kk = 0; kk < KS; kk++)
            #pragma unroll
            for (int ii = 0; ii < BJ/64; ii++)
                GL2LDS(&qk[(size_t)(b*S_ + j0 + w*(BJ/4) + ii*16 + srow)*2048
                           + 1024 + h*DK + kk*32 + ssw],
                       &Ks[kk*BJ*32 + w*(BJ/4)*32 + ii*512]);
        // stage vT: [jchunk][DK rows][32]; wave w d-rows w*(DK/4)+ii*16+srow
        #pragma unroll
        for (int jc = 0; jc < JC; jc++)
            #pragma unroll
            for (int ii = 0; ii < DK/64; ii++)
                GL2LDS(&vT[(size_t)(h*DK + w*(DK/4) + ii*16 + srow)*M_
                           + b*S_ + j0 + jc*32 + ssw],
                       &Vs[jc*DK*32 + w*(DK/4)*32 + ii*512]);
        __syncthreads();

        f32x4 st[JT];
        #pragma unroll
        for (int jt = 0; jt < JT; jt++) {
            f32x4 s = {};
            #pragma unroll
            for (int kk = 0; kk < KS; kk++) {
                half8_t kf = *(const half8_t*)&Ks[kk*BJ*32 + (jt*16 + fr)*32 + k8s];
                s = __builtin_amdgcn_mfma_f32_16x16x32_f16(kf, qf[kk], s, 0, 0, 0);
            }
            st[jt] = s;
        }

        const bool full = (window < 0) || (j0 >= qlo + 15 - window);
        #pragma unroll
        for (int kc = 0; kc < JC; kc++) {
            #pragma unroll
            for (int jh = 0; jh < 2; jh++) {
                int jt = kc*2 + jh;
                float p[4];
                #pragma unroll
                for (int r = 0; r < 4; r++) {
                    float pv = exp2f(st[jt][r] * sc);
                    if (!full) {
                        int jg = j0 + jt*16 + g*4 + r;
                        if (jg < (qlo + fr) - window) pv = 0.f;
                    }
                    p[r] = pv;
                    lsum += pv;
                }
                half4_t ph = {(_Float16)p[0], (_Float16)p[1],
                              (_Float16)p[2], (_Float16)p[3]};
                *(half4_t*)&PsW[fr*LDP + jh*16 + g*4] = ph;
            }
            // same-wave DS ordering: write -> read -> next overwrite is safe
            half8_t pf = *(const half8_t*)&PsW[fr*LDP + k8];
            #pragma unroll
            for (int dt = 0; dt < DT; dt++) {
                half8_t vf = *(const half8_t*)&Vs[kc*DK*32 + (dt*16 + fr)*32 + k8s];
                O[dt] = __builtin_amdgcn_mfma_f32_16x16x32_f16(pf, vf, O[dt], 0, 0, 0);
            }
        }
    }

    lsum += __shfl_xor(lsum, 16);
    lsum += __shfl_xor(lsum, 32);
    if (g == 0) Lw[w*16 + fr] = lsum;
    float linv[4];
    #pragma unroll
    for (int r = 0; r < 4; r++)
        linv[r] = 1.f / Lw[w*16 + g*4 + r];

    if (LOUT && g == 0)
        lout[(size_t)(b*H + h)*S_ + qlo + fr] = lsum;

    #pragma unroll
    for (int r = 0; r < 4; r++) {
        _Float16* cp = ctx + (size_t)(b*S_ + qlo + g*4 + r)*CTXLD + h*DK;
        #pragma unroll
        for (int dt = 0; dt < DT; dt++)
            cp[dt*16 + fr] = (_Float16)(O[dt][r] * linv[r]);
    }
}

// ---------------------------------------------------------------------------
// Mega flash: all three branches in one 2048-block dispatch.
// T1 XCD remap (r3): bid = (hw&7)*256 + hw>>3 (bijective). Each XCD owns
// 256 logically-consecutive blocks = aligned K/V-sharing groups (~2MB < 4MB
// L2). FETCH 364MB -> 44MB measured. Long on XCDs 0-3, s/m on 4-7.
// s/m qblk = r&31 (heavy qblk=0 first within each group).
// ---------------------------------------------------------------------------
__global__ __launch_bounds__(256, 4) void flash_mega(
    const _Float16* __restrict__ qk_s, const _Float16* __restrict__ qk_m,
    const _Float16* __restrict__ qk_l,
    const _Float16* __restrict__ vT_s, const _Float16* __restrict__ vT_m,
    const _Float16* __restrict__ vT_l,
    _Float16* __restrict__ ctxall, float* __restrict__ lbuf)
{
    __shared__ __align__(16) _Float16 lds[18944];
    __shared__ float Lw[64];

    const int hwb = blockIdx.x;
    const int bid = (hwb & 7) * 256 + (hwb >> 3);
    if (bid < 1024) {
        int qblk = bid & 31, h = (bid >> 5) & 15, b = bid >> 9;
        flash_body<64, 128, true>(lds, Lw, qk_l, vT_l, ctxall + 2048, lbuf,
                                  -1, b, h, qblk, 16);
    } else {
        int r = bid - 1024;
        int qblk = r & 31;              // heavy (qblk=0) first within group
        int h = (r >> 5) & 7;
        int z = r >> 8;                 // 0..3 = branch*2 + batch
        int br = z >> 1, b = z & 1;
        flash_body<128, 64, false>(lds, Lw, br ? qk_m : qk_s, br ? vT_m : vT_s,
                                   ctxall + (br ? 1024 : 0), nullptr,
                                   br ? 30 : 10, b, h, qblk, 8);
    }
}

// ---------------------------------------------------------------------------
// Head-averaged long-branch attention probabilities (2 heads per barrier).
// Same T2 swizzle as flash_body on the staged K tile. K-sharing blocks
// (y-varying, hw stride 16) already co-XCD (16%8==0) - no remap needed.
// ---------------------------------------------------------------------------
__global__ __launch_bounds__(256, 4) void attn_mean3(
    const _Float16* __restrict__ qk,
    const float* __restrict__ lbuf,
    float* __restrict__ attn)
{
    __shared__ __align__(16) _Float16 Ks[2 * 2 * 128 * 32];

    const int t = threadIdx.x, lane = t & 63, w = t >> 6;
    const int fr = lane & 15, g = lane >> 4, k8 = g * 8;
    const int k8s = (g ^ ((fr >> 1) & 3)) * 8;
    const int j0 = blockIdx.x * 128;
    const int irow = blockIdx.y * 64 + w * 16;
    const int b = blockIdx.z;
    const float c1 = 0.125f * 1.44269504f;
    const int srow = lane >> 2;
    const int ssw  = ((lane & 3) ^ ((srow >> 1) & 3)) * 8;

    f32x4 acc[8] = {};

    for (int hp = 0; hp < 16; hp += 2) {
        __syncthreads();
        #pragma unroll
        for (int hh = 0; hh < 2; hh++)
            #pragma unroll
            for (int kk = 0; kk < 2; kk++)
                #pragma unroll
                for (int ii = 0; ii < 2; ii++)
                    GL2LDS(&qk[(size_t)(b*S_ + j0 + w*32 + ii*16 + srow)*2048
                               + 1024 + (hp+hh)*64 + kk*32 + ssw],
                           &Ks[hh*8192 + kk*4096 + w*1024 + ii*512]);
        __syncthreads();

        #pragma unroll
        for (int hh = 0; hh < 2; hh++) {
            const int h = hp + hh;
            half8_t af[2];
            #pragma unroll
            for (int kk = 0; kk < 2; kk++)
                af[kk] = *(const half8_t*)
                    &qk[(size_t)(b*S_ + irow + fr)*2048 + h*64 + kk*32 + k8];

            float lg[4];
            #pragma unroll
            for (int r = 0; r < 4; r++)
                lg[r] = __log2f(lbuf[(size_t)(b*16 + h)*S_ + irow + g*4 + r]) + 4.0f;

            #pragma unroll
            for (int nt = 0; nt < 8; nt++) {
                f32x4 s = {};
                #pragma unroll
                for (int kk = 0; kk < 2; kk++) {
                    half8_t bf = *(const half8_t*)
                        &Ks[hh*8192 + kk*4096 + (nt*16 + fr)*32 + k8s];
                    s = __builtin_amdgcn_mfma_f32_16x16x32_f16(af[kk], bf, s, 0, 0, 0);
                }
                #pragma unroll
                for (int r = 0; r < 4; r++)
                    acc[nt][r] += exp2f(s[r] * c1 - lg[r]);
            }
        }
    }

    #pragma unroll
    for (int r = 0; r < 4; r++) {
        float* p = attn + (size_t)(b*S_ + irow + g*4 + r)*S_ + j0;
        #pragma unroll
        for (int nt = 0; nt < 8; nt++)
            p[nt*16 + fr] = acc[nt][r];
    }
}

// ---------------------------------------------------------------------------
// Residual + LayerNorm
// ---------------------------------------------------------------------------
__global__ __launch_bounds__(256) void ln_residual(
    const float* __restrict__ pre, const float* __restrict__ x,
    const float* __restrict__ gamma, const float* __restrict__ beta,
    float* __restrict__ out)
{
    __shared__ float redS[4], redQ[4];
    const int row = blockIdx.x;
    const int t = threadIdx.x;
    size_t base = (size_t)row * D_ + t * 4;

    float4 v  = *(const float4*)(pre + base);
    float4 xv = *(const float4*)(x + base);
    v.x += xv.x; v.y += xv.y; v.z += xv.z; v.w += xv.w;

    float s = v.x + v.y + v.z + v.w;
    float q = v.x*v.x + v.y*v.y + v.z*v.z + v.w*v.w;
    #pragma unroll
    for (int m = 32; m >= 1; m >>= 1) {
        s += __shfl_xor(s, m);
        q += __shfl_xor(q, m);
    }
    int wave = t >> 6;
    if ((t & 63) == 0) { redS[wave] = s; redQ[wave] = q; }
    __syncthreads();
    s = redS[0] + redS[1] + redS[2] + redS[3];
    q = redQ[0] + redQ[1] + redQ[2] + redQ[3];

    float mean = s * (1.f / D_);
    float var  = q * (1.f / D_) - mean * mean;
    float rstd = rsqrtf(var + 1e-5f);

    float4 g  = *(const float4*)(gamma + t * 4);
    float4 be = *(const float4*)(beta + t * 4);
    float4 o;
    o.x = (v.x - mean) * rstd * g.x + be.x;
    o.y = (v.y - mean) * rstd * g.y + be.y;
    o.z = (v.z - mean) * rstd * g.z + be.z;
    o.w = (v.w - mean) * rstd * g.w + be.w;
    *(float4*)(out + base) = o;
}

// ---------------------------------------------------------------------------
extern "C" void kernel_launch(void* const* d_in, const int* in_sizes, int n_in,
                              void* d_out, int out_size, void* d_ws, size_t ws_size,
                              hipStream_t stream)
{
    (void)in_sizes; (void)n_in; (void)out_size; (void)ws_size;
    const float* x      = (const float*)d_in[0];
    const float* w_in_s = (const float*)d_in[1];
    const float* b_in_s = (const float*)d_in[2];
    const float* wo_s   = (const float*)d_in[3];
    const float* bo_s   = (const float*)d_in[4];
    const float* w_in_m = (const float*)d_in[5];
    const float* b_in_m = (const float*)d_in[6];
    const float* wo_m   = (const float*)d_in[7];
    const float* bo_m   = (const float*)d_in[8];
    const float* w_in_l = (const float*)d_in[9];
    const float* b_in_l = (const float*)d_in[10];
    const float* wo_l   = (const float*)d_in[11];
    const float* bo_l   = (const float*)d_in[12];
    const float* w_comb = (const float*)d_in[13];
    const float* b_comb = (const float*)d_in[14];
    const float* gamma  = (const float*)d_in[15];
    const float* beta   = (const float*)d_in[16];

    float* out    = (float*)d_out;                 // [B,S,D]
    float* attn_o = out + (size_t)M_ * D_;         // [B,S,S]

    // Workspace (byte offsets; total ~132.3 MB <= proven-available 134.5 MB).
    // Alias lifetimes (stream order):
    //   w_comb_h+woT_s [18,26)MB dead after weff gemm -> vT_l (qkv_all writes it after)
    //   qk_m dead after flash_mega -> pre (fused gemm output)
    char* W = (char*)d_ws;
    _Float16* w_in_s_h = (_Float16*)(W);                 //  6MB
    _Float16* w_in_m_h = (_Float16*)(W + 6291456);       //  6MB
    _Float16* w_in_l_h = (_Float16*)(W + 12582912);      //  6MB
    _Float16* w_comb_h = (_Float16*)(W + 18874368);      //  6MB (-> vT_l)
    _Float16* woT_s    = (_Float16*)(W + 25165824);      //  2MB (-> vT_l tail)
    _Float16* woT_m    = (_Float16*)(W + 27262976);      //  2MB
    _Float16* woT_l    = (_Float16*)(W + 29360128);      //  2MB
    _Float16* weff     = (_Float16*)(W + 31457280);      //  6MB
    _Float16* qk_s     = (_Float16*)(W + 37748736);      // 16MB
    _Float16* qk_m     = (_Float16*)(W + 54525952);      // 16MB (-> pre fp32)
    _Float16* qk_l     = (_Float16*)(W + 71303168);      // 16MB
    _Float16* vT_s     = (_Float16*)(W + 88080384);      //  8MB
    _Float16* vT_m     = (_Float16*)(W + 96468992);      //  8MB
    _Float16* ctxall   = (_Float16*)(W + 104857600);     // 24MB [4096][3072]
    _Float16* x_h      = (_Float16*)(W + 130023424);     //  8MB
    float*    lbuf     = (float*)   (W + 138412032);     // 256KB
    float*    beff     = (float*)   (W + 138674432);     //  4KB
    _Float16* vT_l     = w_comb_h;                       // 8MB alias (see above)
    float*    pre      = (float*)qk_m;

    dim3 blk(256);
    GemmBatch nil = { nullptr, nullptr, nullptr, nullptr, nullptr };

    // ---- casts: x, w_in x3, w_comb ----
    CastArgs ca;
    ca.s[0]=x;      ca.d[0]=x_h;      ca.nb[0]=4096;
    ca.s[1]=w_in_s; ca.d[1]=w_in_s_h; ca.nb[1]=3072;
    ca.s[2]=w_in_m; ca.d[2]=w_in_m_h; ca.nb[2]=3072;
    ca.s[3]=w_in_l; ca.d[3]=w_in_l_h; ca.nb[3]=3072;
    ca.s[4]=w_comb; ca.d[4]=w_comb_h; ca.nb[4]=3072;
    cast_all<<<dim3(16384), blk, 0, stream>>>(ca);

    // ---- transpose-cast wo_* -> woT_* ----
    transpose_cast_wo<<<dim3(16, 16, 3), blk, 0, stream>>>(
        wo_s, wo_m, wo_l, woT_s, woT_m, woT_l);

    // ---- Weff_b = Wc_b @ wo_b (fp16, no bias); NB=64 -> 384 blocks ----
    GemmBatch we0 = { w_comb_h + 0,    woT_s, nullptr, weff + 0,    nullptr };
    GemmBatch we1 = { w_comb_h + 1024, woT_m, nullptr, weff + 1024, nullptr };
    GemmBatch we2 = { w_comb_h + 2048, woT_l, nullptr, weff + 2048, nullptr };
    gemm_f16<3, 64><<<dim3(8, 16, 3), blk, 0, stream>>>(we0, we1, we2, 3072, 1024, 3072, 1024);

    // ---- beff = b_comb + Wc . bo_cat ----
    beff_kernel<<<dim3(1024), blk, 0, stream>>>(w_comb, b_comb, bo_s, bo_m, bo_l, beff);

    // ---- all three QKV projections in one dispatch (w_comb_h now dead -> vT_l) ----
    GemmBatch qs = { x_h, w_in_s_h, b_in_s, qk_s, vT_s };
    GemmBatch qm = { x_h, w_in_m_h, b_in_m, qk_m, vT_m };
    GemmBatch ql = { x_h, w_in_l_h, b_in_l, qk_l, vT_l };
    gemm_f16<2, 128><<<dim3(M_/128, 3072/128, 3), blk, 0, stream>>>(qs, qm, ql, D_, D_, 2048, D_);

    // ---- mega flash: long + short + medium in one 2048-block dispatch ----
    flash_mega<<<dim3(2048), blk, 0, stream>>>(
        qk_s, qk_m, qk_l, vT_s, vT_m, vT_l, ctxall, lbuf);

    // ---- head-averaged probabilities ----
    attn_mean3<<<dim3(S_/128, S_/64, B_), blk, 0, stream>>>(qk_l, lbuf, attn_o);

    // ---- fused (outproj+combine): pre = ctxall @ weff^T + beff ----
    // NB=64 -> grid 32x16 = 512 blocks = 2/CU (was 256 = 1/CU, zero overlap)
    GemmBatch fb = { ctxall, weff, beff, pre, nullptr };
    gemm_f16<0, 64><<<dim3(M_/128, 1024/64, 1), blk, 0, stream>>>(fb, nil, nil, 3072, 3072, D_, 3072);

    // ---- residual LayerNorm ----
    ln_residual<<<dim3(M_), blk, 0, stream>>>(pre, x, gamma, beta, out);
}